// Round 1
// baseline (524.039 us; speedup 1.0000x reference)
//
#include <hip/hip_runtime.h>
#include <math.h>

#define NHh   8
#define EMB   256
#define HDd   32
#define NVv   6
#define NLl   4
#define NPp   4
#define NZz   4
#define SLENs 5440
#define QQ    1600
#define A_ATTN 3072   // NH*NV*NL*NP*NZ
#define A_OFF  6144   // A_ATTN*2

// ---------------------------------------------------------------------------
// Generic fp32 GEMM: C[m,n] = op( sum_k A[m,k]*B[n,k] + bias[n] )
// A: M x K row-major, B: N x K row-major (i.e. math is A @ B.T)
// MODE 0: plain store C[m*N+n]
// MODE 1: tanh epilogue, plain store
// MODE 2: permuted store for val: m=(v*SLEN+s), n=(h*32+d) ->
//         C[((v*NH+h)*SLEN+s)*HD + d]
// Tiles: BM=BN=64, BK=16, 256 threads, 4x4 accum per thread.
// All problem dims here are multiples of the tiles (1600,32640 %64==0; K=256).
// ---------------------------------------------------------------------------
template <int MODE>
__global__ __launch_bounds__(256) void gemm_kernel(
    const float* __restrict__ A, const float* __restrict__ B,
    const float* __restrict__ bias, float* __restrict__ C,
    int M, int N, int K) {
  __shared__ float As[16][68];  // +4 pad: float4-aligned rows, conflict-light
  __shared__ float Bs[16][68];

  const int tid = threadIdx.x;
  const int tx = tid & 15;        // n-tile coord
  const int ty = tid >> 4;        // m-tile coord
  const int bm = blockIdx.y * 64;
  const int bn = blockIdx.x * 64;

  const int kk = tid & 15;        // k within tile for loads
  const int r0 = tid >> 4;        // base row for loads

  float acc[4][4] = {};

  for (int k0 = 0; k0 < K; k0 += 16) {
#pragma unroll
    for (int r = 0; r < 4; ++r) {
      int m = r0 + r * 16;
      As[kk][m] = A[(size_t)(bm + m) * K + k0 + kk];
      Bs[kk][m] = B[(size_t)(bn + m) * K + k0 + kk];
    }
    __syncthreads();
#pragma unroll
    for (int k = 0; k < 16; ++k) {
      float4 a4 = *(const float4*)&As[k][ty * 4];
      float4 b4 = *(const float4*)&Bs[k][tx * 4];
      float av[4] = {a4.x, a4.y, a4.z, a4.w};
      float bv[4] = {b4.x, b4.y, b4.z, b4.w};
#pragma unroll
      for (int i = 0; i < 4; ++i)
#pragma unroll
        for (int j = 0; j < 4; ++j) acc[i][j] += av[i] * bv[j];
    }
    __syncthreads();
  }

#pragma unroll
  for (int i = 0; i < 4; ++i) {
    int m = bm + ty * 4 + i;
    int v = 0, s = 0;
    if (MODE == 2) { v = m / SLENs; s = m - v * SLENs; }
#pragma unroll
    for (int j = 0; j < 4; ++j) {
      int n = bn + tx * 4 + j;
      float c = acc[i][j];
      if (bias) c += bias[n];
      if (MODE == 1) c = tanhf(c);
      if (MODE == 2) {
        int h = n >> 5, dd = n & 31;
        C[((size_t)(v * NHh + h) * SLENs + s) * HDd + dd] = c;
      } else {
        C[(size_t)m * N + n] = c;
      }
    }
  }
}

// ---------------------------------------------------------------------------
// Softmax over rows of 384 (one wave64 per row, 6 elems/lane).
// attn layout: [q][h*384 + rest] -> row = q*8+h, contiguous 384.
// ---------------------------------------------------------------------------
__global__ __launch_bounds__(256) void softmax_kernel(float* __restrict__ attn) {
  int row = blockIdx.x * 4 + (threadIdx.x >> 6);
  int lane = threadIdx.x & 63;
  float* p = attn + (size_t)row * 384;
  float vals[6];
  float m = -1e30f;
#pragma unroll
  for (int i = 0; i < 6; ++i) {
    vals[i] = p[lane + i * 64];
    m = fmaxf(m, vals[i]);
  }
#pragma unroll
  for (int off = 32; off > 0; off >>= 1) m = fmaxf(m, __shfl_xor(m, off, 64));
  float s = 0.f;
#pragma unroll
  for (int i = 0; i < 6; ++i) {
    vals[i] = __expf(vals[i] - m);
    s += vals[i];
  }
#pragma unroll
  for (int off = 32; off > 0; off >>= 1) s += __shfl_xor(s, off, 64);
  float inv = 1.0f / s;
#pragma unroll
  for (int i = 0; i < 6; ++i) p[lane + i * 64] = vals[i] * inv;
}

// ---------------------------------------------------------------------------
// Deformable sampling + attention-weighted accumulation.
// One block per q (256 threads): tid>>5 = head h, tid&31 = channel d.
// Each 32-lane group loops over the 384 (v,l,p,z) samples for its (q,h),
// does the bilinear gather on val_t[(v,h)] and accumulates attn-weighted.
// ---------------------------------------------------------------------------
__global__ __launch_bounds__(256) void sample_kernel(
    const float* __restrict__ ref, const float* __restrict__ offs,
    const float* __restrict__ attn, const float* __restrict__ val_t,
    float* __restrict__ out_pre) {
  const int q = blockIdx.x;
  const int h = threadIdx.x >> 5;
  const int d = threadIdx.x & 31;

  const int lvlW[4] = {64, 32, 16, 8};
  const int lvlH[4] = {64, 32, 16, 8};
  const int lvlS[4] = {0, 4096, 5120, 5376};

  const float* offs_q = offs + (size_t)q * A_OFF + (size_t)h * (NVv * NLl * NPp * NZz * 2);
  const float* attn_q = attn + (size_t)q * A_ATTN + (size_t)h * (NVv * NLl * NPp * NZz);

  float acc = 0.f;

#pragma unroll
  for (int v = 0; v < NVv; ++v) {
    const float* ref_v = ref + ((size_t)(q * NVv + v) * NLl * NZz) * 2;
#pragma unroll
    for (int l = 0; l < NLl; ++l) {
      const int Wl = lvlW[l], Hl = lvlH[l];
      const float sx = 0.5f * (float)(Wl - 1);
      const float sy = 0.5f * (float)(Hl - 1);
      const float* fbase = val_t + ((size_t)(v * NHh + h) * SLENs + lvlS[l]) * HDd;
      for (int p = 0; p < NPp; ++p) {
#pragma unroll
        for (int z = 0; z < NZz; ++z) {
          int a = ((v * NLl + l) * NPp + p) * NZz + z;
          float w = attn_q[a];
          float ox = offs_q[a * 2 + 0];
          float oy = offs_q[a * 2 + 1];
          float rx = ref_v[(l * NZz + z) * 2 + 0];
          float ry = ref_v[(l * NZz + z) * 2 + 1];
          float x = fminf(1.f, fmaxf(-1.f, rx + ox));
          float y = fminf(1.f, fmaxf(-1.f, ry + oy));
          float xp = (x + 1.f) * sx;
          float yp = (y + 1.f) * sy;
          float x0f = floorf(xp), y0f = floorf(yp);
          float wx = xp - x0f, wy = yp - y0f;
          int x0 = (int)x0f, y0 = (int)y0f;       // xp,yp >= 0 -> trunc == floor
          int x1 = min(x0 + 1, Wl - 1);
          int y1 = min(y0 + 1, Hl - 1);
          const float* r0p = fbase + (size_t)(y0 * Wl) * HDd;
          const float* r1p = fbase + (size_t)(y1 * Wl) * HDd;
          float v00 = r0p[x0 * HDd + d];
          float v01 = r0p[x1 * HDd + d];
          float v10 = r1p[x0 * HDd + d];
          float v11 = r1p[x1 * HDd + d];
          float top = v00 + wx * (v01 - v00);
          float bot = v10 + wx * (v11 - v10);
          acc += w * (top + wy * (bot - top));
        }
      }
    }
  }
  out_pre[(size_t)q * EMB + h * HDd + d] = acc;
}

// ---------------------------------------------------------------------------
extern "C" void kernel_launch(void* const* d_in, const int* in_sizes, int n_in,
                              void* d_out, int out_size, void* d_ws, size_t ws_size,
                              hipStream_t stream) {
  const float* queries    = (const float*)d_in[0];
  const float* ref_points = (const float*)d_in[1];
  const float* value      = (const float*)d_in[2];
  // d_in[3] = value_spatial_shapes (hardcoded: 64,32,16,8)
  const float* Wv    = (const float*)d_in[4];
  const float* Woff  = (const float*)d_in[5];
  const float* boff  = (const float*)d_in[6];
  const float* Wattn = (const float*)d_in[7];
  const float* battn = (const float*)d_in[8];
  const float* Wout  = (const float*)d_in[9];
  float* out = (float*)d_out;

  // Workspace layout (fp32):
  // offs   : Q*6144            = 39.3 MB
  // attn   : Q*3072            = 19.7 MB
  // val_t  : 6*8*5440*32       = 33.4 MB
  // out_pre: Q*256             =  1.6 MB
  float* offs    = (float*)d_ws;
  float* attn    = offs + (size_t)QQ * A_OFF;
  float* val_t   = attn + (size_t)QQ * A_ATTN;
  float* out_pre = val_t + (size_t)NVv * NHh * SLENs * HDd;

  dim3 blk(256);

  // offs = tanh(queries @ Woff.T + boff)
  gemm_kernel<1><<<dim3(A_OFF / 64, QQ / 64), blk, 0, stream>>>(
      queries, Woff, boff, offs, QQ, A_OFF, EMB);
  // attn_raw = queries @ Wattn.T + battn
  gemm_kernel<0><<<dim3(A_ATTN / 64, QQ / 64), blk, 0, stream>>>(
      queries, Wattn, battn, attn, QQ, A_ATTN, EMB);
  // val_t[(v,h,s,d)] = (value @ Wv.T) permuted
  gemm_kernel<2><<<dim3(EMB / 64, (NVv * SLENs) / 64), blk, 0, stream>>>(
      value, Wv, nullptr, val_t, NVv * SLENs, EMB, EMB);
  // softmax over 384 per (q,h): 12800 rows, 4 rows/block
  softmax_kernel<<<(QQ * NHh) / 4, 256, 0, stream>>>(attn);
  // deformable bilinear sampling + weighted accumulation
  sample_kernel<<<QQ, 256, 0, stream>>>(ref_points, offs, attn, val_t, out_pre);
  // out = out_pre @ Wout.T
  gemm_kernel<0><<<dim3(EMB / 64, QQ / 64), blk, 0, stream>>>(
      out_pre, Wout, nullptr, out, QQ, EMB, EMB);
}

// Round 2
// 479.157 us; speedup vs baseline: 1.0937x; 1.0937x over previous
//
#include <hip/hip_runtime.h>
#include <hip/hip_bf16.h>
#include <math.h>

#define NHh   8
#define EMB   256
#define HDd   32
#define NVv   6
#define NLl   4
#define SLENs 5440
#define QQ    1600
#define A_ATTN 3072   // NH*NV*NL*NP*NZ
#define A_OFF  6144   // A_ATTN*2
#define SAMP_TOT (QQ * A_ATTN)   // 4,915,200 samples (q,h,v,l,p,z)

__device__ __forceinline__ unsigned short f2bf(float f) {
  __hip_bfloat16 h = __float2bfloat16(f);
  return *(unsigned short*)&h;
}
__device__ __forceinline__ float bf2f(unsigned int u) {
  return __uint_as_float(u << 16);
}

// ---------------------------------------------------------------------------
// fp32 GEMM: C[m,n] = op( sum_k A[m,k]*B[n,k] + bias[n] )
// A: MxK row-major, B: NxK row-major. BM=64, BN=128, BK=16, 256 thr, 4x8 acc.
// MODE 0: f32 store  MODE 1: tanh + f32 store
// MODE 2: bf16 permuted store: m=(v*SLEN+s), n=(h*32+d) ->
//         bf16 C[((v*8+h)*SLEN+s)*32 + d]
// ---------------------------------------------------------------------------
template <int MODE>
__global__ __launch_bounds__(256) void gemm_kernel(
    const float* __restrict__ A, const float* __restrict__ B,
    const float* __restrict__ bias, void* __restrict__ Cv,
    int M, int N, int K) {
  __shared__ float As[16][68];
  __shared__ float Bs[16][132];

  const int t  = threadIdx.x;
  const int bm = blockIdx.y * 64;
  const int bn = blockIdx.x * 128;

  const int lm = t >> 2;          // 0..63
  const int lk = (t & 3) * 4;     // 0,4,8,12
  const float* Aptr  = A + (size_t)(bm + lm) * K + lk;
  const float* Bptr0 = B + (size_t)(bn + lm) * K + lk;
  const float* Bptr1 = B + (size_t)(bn + 64 + lm) * K + lk;

  const int ty = t >> 4;          // 0..15 -> m chunk (4)
  const int tx = t & 15;          // 0..15 -> n chunks (tx*4, 64+tx*4)

  float acc[4][8] = {};

  for (int k0 = 0; k0 < K; k0 += 16) {
    float4 a  = *(const float4*)(Aptr + k0);
    float4 b0 = *(const float4*)(Bptr0 + k0);
    float4 b1 = *(const float4*)(Bptr1 + k0);
    As[lk + 0][lm] = a.x;  As[lk + 1][lm] = a.y;
    As[lk + 2][lm] = a.z;  As[lk + 3][lm] = a.w;
    Bs[lk + 0][lm] = b0.x; Bs[lk + 1][lm] = b0.y;
    Bs[lk + 2][lm] = b0.z; Bs[lk + 3][lm] = b0.w;
    Bs[lk + 0][64 + lm] = b1.x; Bs[lk + 1][64 + lm] = b1.y;
    Bs[lk + 2][64 + lm] = b1.z; Bs[lk + 3][64 + lm] = b1.w;
    __syncthreads();
#pragma unroll
    for (int k = 0; k < 16; ++k) {
      float4 av  = *(const float4*)&As[k][ty * 4];
      float4 bv0 = *(const float4*)&Bs[k][tx * 4];
      float4 bv1 = *(const float4*)&Bs[k][64 + tx * 4];
      float am[4] = {av.x, av.y, av.z, av.w};
      float bn8[8] = {bv0.x, bv0.y, bv0.z, bv0.w, bv1.x, bv1.y, bv1.z, bv1.w};
#pragma unroll
      for (int i = 0; i < 4; ++i)
#pragma unroll
        for (int j = 0; j < 8; ++j) acc[i][j] = fmaf(am[i], bn8[j], acc[i][j]);
    }
    __syncthreads();
  }

  float bv[8] = {};
  if (MODE != 2 && bias) {
#pragma unroll
    for (int j = 0; j < 8; ++j)
      bv[j] = bias[bn + (j < 4 ? tx * 4 + j : 64 + tx * 4 + j - 4)];
  }

#pragma unroll
  for (int i = 0; i < 4; ++i) {
    int m = bm + ty * 4 + i;
    if (MODE == 2) {
      unsigned short* C = (unsigned short*)Cv;
      int vv = m / SLENs;
      int s  = m - vv * SLENs;
#pragma unroll
      for (int c = 0; c < 2; ++c) {
        int n0 = bn + c * 64 + tx * 4;
        int hh = n0 >> 5, dd = n0 & 31;
        ushort4 u;
        u.x = f2bf(acc[i][c * 4 + 0]);
        u.y = f2bf(acc[i][c * 4 + 1]);
        u.z = f2bf(acc[i][c * 4 + 2]);
        u.w = f2bf(acc[i][c * 4 + 3]);
        *(ushort4*)&C[((size_t)(vv * 8 + hh) * SLENs + s) * 32 + dd] = u;
      }
    } else {
      float* C = (float*)Cv;
      float r[8];
#pragma unroll
      for (int j = 0; j < 8; ++j) {
        float c = acc[i][j] + bv[j];
        if (MODE == 1) c = tanhf(c);
        r[j] = c;
      }
      *(float4*)&C[(size_t)m * N + bn + tx * 4]      = make_float4(r[0], r[1], r[2], r[3]);
      *(float4*)&C[(size_t)m * N + bn + 64 + tx * 4] = make_float4(r[4], r[5], r[6], r[7]);
    }
  }
}

// ---------------------------------------------------------------------------
// Softmax over rows of 384 (one wave64 per row, 6 elems/lane).
// ---------------------------------------------------------------------------
__global__ __launch_bounds__(256) void softmax_kernel(float* __restrict__ attn) {
  int row = blockIdx.x * 4 + (threadIdx.x >> 6);
  int lane = threadIdx.x & 63;
  float* p = attn + (size_t)row * 384;
  float vals[6];
  float m = -1e30f;
#pragma unroll
  for (int i = 0; i < 6; ++i) {
    vals[i] = p[lane + i * 64];
    m = fmaxf(m, vals[i]);
  }
#pragma unroll
  for (int off = 32; off > 0; off >>= 1) m = fmaxf(m, __shfl_xor(m, off, 64));
  float s = 0.f;
#pragma unroll
  for (int i = 0; i < 6; ++i) {
    vals[i] = __expf(vals[i] - m);
    s += vals[i];
  }
#pragma unroll
  for (int off = 32; off > 0; off >>= 1) s += __shfl_xor(s, off, 64);
  float inv = 1.0f / s;
#pragma unroll
  for (int i = 0; i < 6; ++i) p[lane + i * 64] = vals[i] * inv;
}

// ---------------------------------------------------------------------------
// Per-sample record precompute: one thread per (q,h,v,l,p,z).
// rec = { int (byte_base<<0 | fx | fy<<1), wx, wy, w }  (byte base = elem*64,
// i.e. bf16 slice layout (s,d): s*32ch*2B; low 6 bits free for flags)
// ---------------------------------------------------------------------------
__global__ __launch_bounds__(256) void precompute_kernel(
    const float* __restrict__ ref, const float* __restrict__ offs,
    const float* __restrict__ attn, float4* __restrict__ rec) {
  int idx = blockIdx.x * 256 + threadIdx.x;   // < SAMP_TOT
  int q   = idx / A_ATTN;
  int rem = idx - q * A_ATTN;
  int v = (rem >> 6) % 6;
  int l = (rem >> 4) & 3;
  int z = rem & 3;

  float  w = attn[idx];
  float2 o = ((const float2*)offs)[idx];
  const float* rp = ref + ((size_t)((q * 6 + v) * 4 + l) * 4 + z) * 2;
  float rx = rp[0], ry = rp[1];

  int Wl = 64 >> l;
  int start = (l == 0) ? 0 : (l == 1 ? 4096 : (l == 2 ? 5120 : 5376));
  float sc = 0.5f * (float)(Wl - 1);

  float x = fminf(1.f, fmaxf(-1.f, rx + o.x));
  float y = fminf(1.f, fmaxf(-1.f, ry + o.y));
  float xp = (x + 1.f) * sc;
  float yp = (y + 1.f) * sc;
  float x0f = floorf(xp), y0f = floorf(yp);
  int x0 = (int)x0f, y0 = (int)y0f;      // xp,yp >= 0 -> trunc == floor
  float wx = xp - x0f, wy = yp - y0f;
  int fx = (x0 + 1 < Wl) ? 1 : 0;
  int fy = (y0 + 1 < Wl) ? 2 : 0;
  int base = ((start + y0 * Wl + x0) << 6) | fx | fy;

  rec[idx] = make_float4(__int_as_float(base), wx, wy, w);
}

// ---------------------------------------------------------------------------
// Sampling: block -> (h = b&7 for XCD L2 affinity, 8 q's). 32-lane group per
// q: iterates 384 records, 4 bf16 gathers off a wave-uniform slice base.
// ---------------------------------------------------------------------------
__global__ __launch_bounds__(256) void sample_kernel(
    const float4* __restrict__ rec, const unsigned short* __restrict__ val_t,
    float* __restrict__ out_pre) {
  const int b  = blockIdx.x;
  const int h  = b & 7;           // XCD b%8 sees only its h -> 6 slices ~2.1MB
  const int qt = b >> 3;
  const int g  = threadIdx.x >> 5;
  const int d2 = (threadIdx.x & 31) << 1;   // byte offset of channel
  const int q  = qt * 8 + g;

  const float4* r = rec + (size_t)q * A_ATTN + h * 384;
  float acc = 0.f;
  int ri = 0;

#pragma unroll
  for (int v = 0; v < 6; ++v) {
    const char* sb = (const char*)(val_t + (size_t)(v * 8 + h) * SLENs * 32);
#pragma unroll
    for (int l = 0; l < 4; ++l) {
#pragma unroll 4
      for (int i = 0; i < 16; ++i) {
        float4 rc = r[ri++];
        int bf = __float_as_int(rc.x);
        int b0 = (bf & -64) + d2;
        int dx = (bf & 1) << 6;
        int dy = (bf & 2) << (11 - l);   // (fy?1:0) * Wl*64 bytes
        float v00 = bf2f(*(const unsigned short*)(sb + b0));
        float v01 = bf2f(*(const unsigned short*)(sb + b0 + dx));
        float v10 = bf2f(*(const unsigned short*)(sb + b0 + dy));
        float v11 = bf2f(*(const unsigned short*)(sb + b0 + dx + dy));
        float wx = rc.y, wy = rc.z, w = rc.w;
        float wxw = wx * w, wmx = w - wxw;
        float w11 = wxw * wy, w01 = wxw - w11;
        float w10 = wmx * wy, w00 = wmx - w10;
        acc = fmaf(w00, v00, acc);
        acc = fmaf(w01, v01, acc);
        acc = fmaf(w10, v10, acc);
        acc = fmaf(w11, v11, acc);
      }
    }
  }
  out_pre[(size_t)q * EMB + h * 32 + (d2 >> 1)] = acc;
}

// ---------------------------------------------------------------------------
extern "C" void kernel_launch(void* const* d_in, const int* in_sizes, int n_in,
                              void* d_out, int out_size, void* d_ws, size_t ws_size,
                              hipStream_t stream) {
  const float* queries    = (const float*)d_in[0];
  const float* ref_points = (const float*)d_in[1];
  const float* value      = (const float*)d_in[2];
  const float* Wv    = (const float*)d_in[4];
  const float* Woff  = (const float*)d_in[5];
  const float* boff  = (const float*)d_in[6];
  const float* Wattn = (const float*)d_in[7];
  const float* battn = (const float*)d_in[8];
  const float* Wout  = (const float*)d_in[9];
  float* out = (float*)d_out;

  // ws layout (rec first: 16B aligned)
  float4* rec     = (float4*)d_ws;                                  // 78.6 MB
  float*  offs    = (float*)(rec + (size_t)SAMP_TOT);               // 39.3 MB
  float*  attn    = offs + (size_t)QQ * A_OFF;                      // 19.7 MB
  unsigned short* val_t = (unsigned short*)(attn + (size_t)QQ * A_ATTN); // 16.7 MB
  float*  out_pre = (float*)(val_t + (size_t)NVv * NHh * SLENs * HDd);   // 1.6 MB

  dim3 blk(256);

  // offs = tanh(queries @ Woff.T + boff)
  gemm_kernel<1><<<dim3(A_OFF / 128, QQ / 64), blk, 0, stream>>>(
      queries, Woff, boff, offs, QQ, A_OFF, EMB);
  // attn_raw = queries @ Wattn.T + battn
  gemm_kernel<0><<<dim3(A_ATTN / 128, QQ / 64), blk, 0, stream>>>(
      queries, Wattn, battn, attn, QQ, A_ATTN, EMB);
  // softmax per (q,h) over 384
  softmax_kernel<<<(QQ * NHh) / 4, blk, 0, stream>>>(attn);
  // val_t (bf16, [v][h][s][d]) = (value @ Wv.T) permuted
  gemm_kernel<2><<<dim3(EMB / 128, (NVv * SLENs) / 64), blk, 0, stream>>>(
      value, Wv, nullptr, val_t, NVv * SLENs, EMB, EMB);
  // per-sample records
  precompute_kernel<<<SAMP_TOT / 256, blk, 0, stream>>>(
      ref_points, offs, attn, rec);
  // bilinear sampling + weighted accumulation
  sample_kernel<<<QQ * NHh / 8, blk, 0, stream>>>(rec, val_t, out_pre);
  // out = out_pre @ Wout.T
  gemm_kernel<0><<<dim3(EMB / 128, QQ / 64), blk, 0, stream>>>(
      out_pre, Wout, nullptr, out, QQ, EMB, EMB);
}

// Round 4
// 387.723 us; speedup vs baseline: 1.3516x; 1.2358x over previous
//
#include <hip/hip_runtime.h>
#include <hip/hip_bf16.h>
#include <math.h>

#define NHh   8
#define EMB   256
#define HDd   32
#define NVv   6
#define NLl   4
#define SLENs 5440
#define QQ    1600
#define A_ATTN 3072   // NH*NV*NL*NP*NZ
#define A_OFF  6144   // A_ATTN*2
#define SAMP_TOT (QQ * A_ATTN)   // 4,915,200 samples (q,h,v,l,p,z)

typedef __attribute__((ext_vector_type(8))) short short8;
typedef __attribute__((ext_vector_type(4))) float f32x4;

__device__ __forceinline__ unsigned short f2bf(float f) {
  __hip_bfloat16 h = __float2bfloat16(f);
  return *(unsigned short*)&h;
}
__device__ __forceinline__ float bfbits2f(unsigned short u) {
  return __uint_as_float((unsigned int)u << 16);
}
__device__ __forceinline__ void split1(float x, unsigned short& h, unsigned short& l) {
  h = f2bf(x);
  l = f2bf(x - bfbits2f(h));
}

// ---------------------------------------------------------------------------
// Split-bf16 MFMA GEMM: C[m,n] = op( A[m,:]·B[n,:] + bias[n] )
// A: MxK fp32 row-major, B: NxK fp32 row-major.
// fp32 split into hi+lo bf16 during LDS staging; 3 MFMAs per tile-pair
// (hh + hl + lh) -> ~2^-17 relative error, far below the fp32-path budget.
// Tile 128x128, BK=32, 256 threads = 4 waves in 2x2 of 64x64 quadrants.
// MODE 0: f32 store  MODE 1: tanh + f32 store
// MODE 2: bf16 permuted store: m=(v*SLEN+s), n=(h*32+d) ->
//         bf16 C[((v*8+h)*SLEN+s)*32 + d]
// M may be non-multiple of 128 (loads clamped, stores guarded); N%128==0.
// ---------------------------------------------------------------------------
template <int MODE>
__global__ __launch_bounds__(256) void gemm3_kernel(
    const float* __restrict__ A, const float* __restrict__ B,
    const float* __restrict__ bias, void* __restrict__ Cv,
    int M, int N, int K) {
  __shared__ unsigned short Ah[128 * 32], Al[128 * 32];
  __shared__ unsigned short Bh[128 * 32], Bl[128 * 32];

  const int tid = threadIdx.x;
  const int bm = blockIdx.y * 128;
  const int bn = blockIdx.x * 128;
  const int lane = tid & 63;
  const int w = tid >> 6;
  const int wm = (w & 1) * 64;
  const int wn = (w >> 1) * 64;
  const int l16 = lane & 15;
  const int quad = lane >> 4;

  // staging addresses (fixed across k-loop)
  const int r0 = tid >> 3;
  const int kc = (tid & 7) << 2;
  const float* aP[4];
  const float* bP[4];
  int lofs[4];
#pragma unroll
  for (int rep = 0; rep < 4; ++rep) {
    int r = r0 + rep * 32;
    aP[rep] = A + (size_t)min(bm + r, M - 1) * K + kc;
    bP[rep] = B + (size_t)(bn + r) * K + kc;
    lofs[rep] = r * 32 + kc;
  }

  f32x4 acc[4][4] = {};

  for (int k0 = 0; k0 < K; k0 += 32) {
#pragma unroll
    for (int rep = 0; rep < 4; ++rep) {
      float4 a4 = *(const float4*)(aP[rep] + k0);
      float4 b4 = *(const float4*)(bP[rep] + k0);
      ushort4 ah4, al4, bh4, bl4;
      split1(a4.x, ah4.x, al4.x); split1(a4.y, ah4.y, al4.y);
      split1(a4.z, ah4.z, al4.z); split1(a4.w, ah4.w, al4.w);
      split1(b4.x, bh4.x, bl4.x); split1(b4.y, bh4.y, bl4.y);
      split1(b4.z, bh4.z, bl4.z); split1(b4.w, bh4.w, bl4.w);
      *(ushort4*)&Ah[lofs[rep]] = ah4;
      *(ushort4*)&Al[lofs[rep]] = al4;
      *(ushort4*)&Bh[lofs[rep]] = bh4;
      *(ushort4*)&Bl[lofs[rep]] = bl4;
    }
    __syncthreads();

    short8 fah[4], fal[4], fbh[4], fbl[4];
#pragma unroll
    for (int i = 0; i < 4; ++i) {
      int ar = (wm + i * 16 + l16) * 32 + quad * 8;
      int br = (wn + i * 16 + l16) * 32 + quad * 8;
      fah[i] = *(const short8*)&Ah[ar];
      fal[i] = *(const short8*)&Al[ar];
      fbh[i] = *(const short8*)&Bh[br];
      fbl[i] = *(const short8*)&Bl[br];
    }
#pragma unroll
    for (int i = 0; i < 4; ++i)
#pragma unroll
      for (int j = 0; j < 4; ++j) {
        acc[i][j] = __builtin_amdgcn_mfma_f32_16x16x32_bf16(fah[i], fbh[j], acc[i][j], 0, 0, 0);
        acc[i][j] = __builtin_amdgcn_mfma_f32_16x16x32_bf16(fah[i], fbl[j], acc[i][j], 0, 0, 0);
        acc[i][j] = __builtin_amdgcn_mfma_f32_16x16x32_bf16(fal[i], fbh[j], acc[i][j], 0, 0, 0);
      }
    __syncthreads();
  }

  // epilogue: C/D layout col(n)=lane&15, row(m)=quad*4+reg  [m89-verified]
#pragma unroll
  for (int j = 0; j < 4; ++j) {
    int n = bn + wn + j * 16 + l16;
    float bv = 0.f;
    if (MODE != 2 && bias) bv = bias[n];
#pragma unroll
    for (int i = 0; i < 4; ++i) {
      int mbase = bm + wm + i * 16 + quad * 4;
#pragma unroll
      for (int reg = 0; reg < 4; ++reg) {
        int m = mbase + reg;
        if (m >= M) continue;
        float c = acc[i][j][reg] + bv;
        if (MODE == 1) {  // tanh: 1 - 2/(e^2x + 1), err ~1.5e-7
          float t = __expf(2.f * c);
          c = 1.f - 2.f / (t + 1.f);
        }
        if (MODE == 2) {
          int vv = m / SLENs;
          int s = m - vv * SLENs;
          int hh = n >> 5, dd = n & 31;
          ((unsigned short*)Cv)[((size_t)(vv * 8 + hh) * SLENs + s) * 32 + dd] = f2bf(c);
        } else {
          ((float*)Cv)[(size_t)m * N + n] = c;
        }
      }
    }
  }
}

// ---------------------------------------------------------------------------
// Softmax over rows of 384 (one wave64 per row, 6 elems/lane).
// ---------------------------------------------------------------------------
__global__ __launch_bounds__(256) void softmax_kernel(float* __restrict__ attn) {
  int row = blockIdx.x * 4 + (threadIdx.x >> 6);
  int lane = threadIdx.x & 63;
  float* p = attn + (size_t)row * 384;
  float vals[6];
  float m = -1e30f;
#pragma unroll
  for (int i = 0; i < 6; ++i) {
    vals[i] = p[lane + i * 64];
    m = fmaxf(m, vals[i]);
  }
#pragma unroll
  for (int off = 32; off > 0; off >>= 1) m = fmaxf(m, __shfl_xor(m, off, 64));
  float s = 0.f;
#pragma unroll
  for (int i = 0; i < 6; ++i) {
    vals[i] = __expf(vals[i] - m);
    s += vals[i];
  }
#pragma unroll
  for (int off = 32; off > 0; off >>= 1) s += __shfl_xor(s, off, 64);
  float inv = 1.0f / s;
#pragma unroll
  for (int i = 0; i < 6; ++i) p[lane + i * 64] = vals[i] * inv;
}

// ---------------------------------------------------------------------------
// Per-sample records: one thread per (q,h,v,l,p,z).
// rec = { int (elem_base<<6 | fx | fy<<1), wx*w, w - wx*w, wy }
// ---------------------------------------------------------------------------
__global__ __launch_bounds__(256) void precompute_kernel(
    const float* __restrict__ ref, const float* __restrict__ offs,
    const float* __restrict__ attn, float4* __restrict__ rec) {
  int idx = blockIdx.x * 256 + threadIdx.x;   // < SAMP_TOT
  int q   = idx / A_ATTN;
  int rem = idx - q * A_ATTN;
  int v = (rem >> 6) % 6;
  int l = (rem >> 4) & 3;
  int z = rem & 3;

  float  w = attn[idx];
  float2 o = ((const float2*)offs)[idx];
  const float* rp = ref + ((size_t)((q * 6 + v) * 4 + l) * 4 + z) * 2;
  float rx = rp[0], ry = rp[1];

  int Wl = 64 >> l;
  int start = (l == 0) ? 0 : (l == 1 ? 4096 : (l == 2 ? 5120 : 5376));
  float sc = 0.5f * (float)(Wl - 1);

  float x = fminf(1.f, fmaxf(-1.f, rx + o.x));
  float y = fminf(1.f, fmaxf(-1.f, ry + o.y));
  float xp = (x + 1.f) * sc;
  float yp = (y + 1.f) * sc;
  float x0f = floorf(xp), y0f = floorf(yp);
  int x0 = (int)x0f, y0 = (int)y0f;      // xp,yp >= 0 -> trunc == floor
  float wx = xp - x0f, wy = yp - y0f;
  int fx = (x0 + 1 < Wl) ? 1 : 0;
  int fy = (y0 + 1 < Wl) ? 2 : 0;
  int base = ((start + y0 * Wl + x0) << 6) | fx | fy;

  float wxw = wx * w;
  rec[idx] = make_float4(__int_as_float(base), wxw, w - wxw, wy);
}

// ---------------------------------------------------------------------------
// Sampling v2: wave = one (q,h). Lane = (r = rec parity, c = corner,
// e = channel quad): lane>>5 = r, (lane>>3)&3 = c, lane&7 = e.
// Each iteration: wave consumes 2 records; each lane does ONE uint2 gather
// (4 bf16 channels of its corner). Butterfly-reduce over lane bits 3/4/5.
// Block = 4 waves = 4 q's of the same h; blockIdx&7 = h for XCD L2 affinity.
// ---------------------------------------------------------------------------
__global__ __launch_bounds__(256) void sample_kernel(
    const float4* __restrict__ rec, const unsigned short* __restrict__ val_t,
    float* __restrict__ out_pre) {
  const int h  = blockIdx.x & 7;
  const int qt = blockIdx.x >> 3;
  const int lane = threadIdx.x & 63;
  const int q  = qt * 4 + (threadIdx.x >> 6);

  const int r   = lane >> 5;
  const bool cx = (lane >> 3) & 1;
  const bool cy = (lane >> 4) & 1;
  const int cm1 = -(int)((lane >> 3) & 1);   // mask: corner needs +dx
  const int cm2 = -(int)((lane >> 4) & 1);   // mask: corner needs +dy
  const int e8  = (lane & 7) << 3;           // byte offset of channel quad

  const float4* rptr = rec + (size_t)q * A_ATTN + h * 384;
  float4 acc = make_float4(0.f, 0.f, 0.f, 0.f);
  int ib = r;

#pragma unroll
  for (int v = 0; v < 6; ++v) {
    const char* sb = (const char*)val_t + (size_t)(v * 8 + h) * (SLENs * 64);
#pragma unroll
    for (int l = 0; l < 4; ++l) {
#pragma unroll 4
      for (int i = 0; i < 8; ++i) {
        float4 rc = rptr[ib];
        ib += 2;
        int bf = __float_as_int(rc.x);
        int b0 = bf & -64;
        int ox = ((bf & 1) << 6) & cm1;
        int oy = ((bf & 2) << (11 - l)) & cm2;
        uint2 u = *(const uint2*)(sb + (b0 + ox + oy + e8));
        float v0 = __uint_as_float(u.x << 16);          // bf16 ch 4e+0
        float v1 = __uint_as_float(u.x & 0xFFFF0000u);  // bf16 ch 4e+1
        float v2 = __uint_as_float(u.y << 16);          // bf16 ch 4e+2
        float v3 = __uint_as_float(u.y & 0xFFFF0000u);  // bf16 ch 4e+3
        float s1 = cx ? rc.y : rc.z;        // wx*w : (1-wx)*w
        float s2 = cy ? rc.w : 1.f - rc.w;  // wy   : 1-wy
        float wl = s1 * s2;
        acc.x = fmaf(wl, v0, acc.x);
        acc.y = fmaf(wl, v1, acc.y);
        acc.z = fmaf(wl, v2, acc.z);
        acc.w = fmaf(wl, v3, acc.w);
      }
    }
  }

  // reduce over corner bits (8,16) and record parity (32)
#pragma unroll
  for (int m = 8; m <= 32; m <<= 1) {
    acc.x += __shfl_xor(acc.x, m, 64);
    acc.y += __shfl_xor(acc.y, m, 64);
    acc.z += __shfl_xor(acc.z, m, 64);
    acc.w += __shfl_xor(acc.w, m, 64);
  }
  if (lane < 8)
    *(float4*)&out_pre[(size_t)q * EMB + h * 32 + lane * 4] = acc;
}

// ---------------------------------------------------------------------------
extern "C" void kernel_launch(void* const* d_in, const int* in_sizes, int n_in,
                              void* d_out, int out_size, void* d_ws, size_t ws_size,
                              hipStream_t stream) {
  const float* queries    = (const float*)d_in[0];
  const float* ref_points = (const float*)d_in[1];
  const float* value      = (const float*)d_in[2];
  const float* Wv    = (const float*)d_in[4];
  const float* Woff  = (const float*)d_in[5];
  const float* boff  = (const float*)d_in[6];
  const float* Wattn = (const float*)d_in[7];
  const float* battn = (const float*)d_in[8];
  const float* Wout  = (const float*)d_in[9];
  float* out = (float*)d_out;

  // ws layout (identical footprint to round 2 -> known to fit)
  float4* rec     = (float4*)d_ws;                                  // 78.6 MB
  float*  offs    = (float*)(rec + (size_t)SAMP_TOT);               // 39.3 MB
  float*  attn    = offs + (size_t)QQ * A_OFF;                      // 19.7 MB
  unsigned short* val_t = (unsigned short*)(attn + (size_t)QQ * A_ATTN); // 16.7 MB
  float*  out_pre = (float*)(val_t + (size_t)NVv * NHh * SLENs * HDd);   // 1.6 MB

  dim3 blk(256);

  // offs = tanh(queries @ Woff.T + boff)
  gemm3_kernel<1><<<dim3(A_OFF / 128, (QQ + 127) / 128), blk, 0, stream>>>(
      queries, Woff, boff, offs, QQ, A_OFF, EMB);
  // attn_raw = queries @ Wattn.T + battn
  gemm3_kernel<0><<<dim3(A_ATTN / 128, (QQ + 127) / 128), blk, 0, stream>>>(
      queries, Wattn, battn, attn, QQ, A_ATTN, EMB);
  // softmax per (q,h) over 384
  softmax_kernel<<<(QQ * NHh) / 4, blk, 0, stream>>>(attn);
  // val_t (bf16, [v][h][s][d]) = (value @ Wv.T) permuted
  gemm3_kernel<2><<<dim3(EMB / 128, (NVv * SLENs) / 128), blk, 0, stream>>>(
      value, Wv, nullptr, val_t, NVv * SLENs, EMB, EMB);
  // per-sample records
  precompute_kernel<<<SAMP_TOT / 256, blk, 0, stream>>>(
      ref_points, offs, attn, rec);
  // bilinear sampling + weighted accumulation
  sample_kernel<<<QQ * NHh / 4, blk, 0, stream>>>(rec, val_t, out_pre);
  // out = out_pre @ Wout.T
  gemm3_kernel<0><<<dim3(EMB / 128, (QQ + 127) / 128), blk, 0, stream>>>(
      out_pre, Wout, nullptr, out, QQ, EMB, EMB);
}